// Round 2
// baseline (575.523 us; speedup 1.0000x reference)
//
#include <hip/hip_runtime.h>

#define H 4096
#define O 4096
#define HO 8192
#define MAXLEN 15
#define CHUNK 256   // floats per 1KB stage instruction (64 lanes x 16B)

typedef const __attribute__((address_space(1))) unsigned int* as1_u32p;
typedef __attribute__((address_space(3))) unsigned int* as3_u32p;

// One global_load_lds_dwordx4: 64 lanes x 16B -> 1KB into LDS at uniform base.
// Per-lane global src = g (already offset by lane*16B); LDS dst = l + lane*16B.
__device__ __forceinline__ void stage1k(const float* g, float* l) {
    __builtin_amdgcn_global_load_lds((as1_u32p)g, (as3_u32p)l, 16, 0, 0);
}

#define WAITV(N) asm volatile("s_waitcnt vmcnt(" #N ")" ::: "memory")
#define REGION_FENCE() do { asm volatile("" ::: "memory"); __builtin_amdgcn_sched_barrier(0); } while (0)

// 2-row matvec, weights staged global->LDS with depth-1 prefetch, no barriers.
// sst: per-wave private staging, 4*CHUNK floats (2 buffers x 2 rows x CHUNK).
// Steady-state vmcnt window per chunk: 2 stage instrs + 1 x float4 load = 3.
__device__ __forceinline__ void mv2(const float* __restrict__ W, int row, int K, int NC,
                                    const float* __restrict__ x, float* sst, int lane,
                                    float& out0, float& out1) {
    const float* wr0 = W + (size_t)row * K;
    const float* wr1 = wr0 + K;
    // prologue: chunk 0 (2 stages + x load), then fence so the vmcnt regions are exact
    stage1k(wr0 + lane * 4, sst);
    stage1k(wr1 + lane * 4, sst + CHUNK);
    float4 xcur = *(const float4*)(x + lane * 4);
    REGION_FENCE();
    float acc0 = 0.f, acc1 = 0.f;
    for (int t = 0; t < NC; ++t) {
        float4 xnext = xcur;
        if (t + 1 < NC) {
            const int b = ((t + 1) & 1) * (2 * CHUNK);
            stage1k(wr0 + (size_t)(t + 1) * CHUNK + lane * 4, sst + b);
            stage1k(wr1 + (size_t)(t + 1) * CHUNK + lane * 4, sst + b + CHUNK);
            xnext = *(const float4*)(x + (size_t)(t + 1) * CHUNK + lane * 4);
            WAITV(3);   // all but this iteration's {2 stages, 1 x-load} retired -> chunk t in LDS
        } else {
            WAITV(0);   // drain for the final chunk
        }
        __builtin_amdgcn_sched_barrier(0);
        const int rb = (t & 1) * (2 * CHUNK);
        float4 a  = *(const float4*)(sst + rb + lane * 4);
        float4 b4 = *(const float4*)(sst + rb + CHUNK + lane * 4);
        acc0 += a.x  * xcur.x + a.y  * xcur.y + a.z  * xcur.z + a.w  * xcur.w;
        acc1 += b4.x * xcur.x + b4.y * xcur.y + b4.z * xcur.z + b4.w * xcur.w;
        xcur = xnext;
    }
    #pragma unroll
    for (int off = 32; off; off >>= 1) {
        acc0 += __shfl_down(acc0, off, 64);
        acc1 += __shfl_down(acc1, off, 64);
    }
    out0 = acc0; out1 = acc1;
}

// K1a: attention logits, one block per attention row.
__global__ __launch_bounds__(1024) void k_attlogit(const int* __restrict__ ids,
                                                   const float* __restrict__ hidden,
                                                   const float* __restrict__ embW,
                                                   const float* __restrict__ attW,
                                                   const float* __restrict__ attb,
                                                   float* __restrict__ attlog) {
    __shared__ float sred[16];
    const int tid = threadIdx.x, lane = tid & 63, wave = tid >> 6;
    const int j = blockIdx.x;
    const float* emb = embW + (size_t)ids[0] * O;
    const float4* w4 = (const float4*)(attW + (size_t)j * (H + O));
    const float4* e4 = (const float4*)emb;
    const float4* h4 = (const float4*)hidden;

    float4 wv0 = w4[tid];
    float4 xv0 = e4[tid];
    float4 wv1 = w4[tid + 1024];
    float4 xv1 = h4[tid];
    float acc = wv0.x * xv0.x + wv0.y * xv0.y + wv0.z * xv0.z + wv0.w * xv0.w
              + wv1.x * xv1.x + wv1.y * xv1.y + wv1.z * xv1.z + wv1.w * xv1.w;
    #pragma unroll
    for (int off = 32; off; off >>= 1) acc += __shfl_down(acc, off, 64);
    if (lane == 0) sred[wave] = acc;
    __syncthreads();
    if (tid == 0) {
        float s = 0.f;
        #pragma unroll
        for (int w = 0; w < 16; w++) s += sred[w];
        attlog[j] = s + attb[j];
    }
}

// K1b: softmax(15) per-thread + att_applied + emb copy into combined.
__global__ __launch_bounds__(256) void k_attapply(const int* __restrict__ ids,
                                                  const float* __restrict__ embW,
                                                  const float* __restrict__ attlog,
                                                  const float* __restrict__ eseq,
                                                  float* __restrict__ combined,
                                                  float* __restrict__ out_attw) {
    const int k = blockIdx.x * 256 + threadIdx.x;   // 0..4095
    float l[MAXLEN];
    float m = -1e30f;
    #pragma unroll
    for (int j = 0; j < MAXLEN; j++) { l[j] = attlog[j]; m = fmaxf(m, l[j]); }
    float s = 0.f;
    #pragma unroll
    for (int j = 0; j < MAXLEN; j++) { l[j] = __expf(l[j] - m); s += l[j]; }
    const float inv = 1.f / s;

    float acc = 0.f;
    #pragma unroll
    for (int j = 0; j < MAXLEN; j++) acc += l[j] * eseq[j * H + k];
    combined[O + k] = acc * inv;
    combined[k] = embW[(size_t)ids[0] * O + k];
    if (blockIdx.x == 0 && threadIdx.x < MAXLEN) out_attw[threadIdx.x] = l[threadIdx.x] * inv;
}

// K2: every block identical: waves 0-1 -> 4 comb rows (K=8192, relu),
//     waves 2-7 -> 12 ghh rows (K=4096). 1024 blocks = 4/CU, one round.
__global__ __launch_bounds__(512) void k_mvA(const float* __restrict__ combW,
                                             const float* __restrict__ combB,
                                             const float* __restrict__ ghhW,
                                             const float* __restrict__ ghhB,
                                             const float* __restrict__ hidden,
                                             const float* __restrict__ combined,
                                             float* __restrict__ xout,
                                             float* __restrict__ ghout) {
    __shared__ __align__(16) float sst[8 * 4 * CHUNK];   // 32KB: 8 waves x (2buf x 2row x 1KB)
    const int wave = threadIdx.x >> 6, lane = threadIdx.x & 63;
    float* st = sst + wave * 4 * CHUNK;
    float r0, r1;
    if (wave < 2) {
        const int row = blockIdx.x * 4 + wave * 2;            // 0..4094
        mv2(combW, row, HO, HO / CHUNK, combined, st, lane, r0, r1);
        if (lane == 0) {
            xout[row]     = fmaxf(r0 + combB[row], 0.f);
            xout[row + 1] = fmaxf(r1 + combB[row + 1], 0.f);
        }
    } else {
        const int row = blockIdx.x * 12 + (wave - 2) * 2;     // 0..12286
        mv2(ghhW, row, H, H / CHUNK, hidden, st, lane, r0, r1);
        if (lane == 0) {
            ghout[row]     = r0 + ghhB[row];
            ghout[row + 1] = r1 + ghhB[row + 1];
        }
    }
}

// K3: gi = gru_W_ih @ x + b_ih. 768 blocks x 16 rows.
__global__ __launch_bounds__(512) void k_mvB(const float* __restrict__ gihW,
                                             const float* __restrict__ gihB,
                                             const float* __restrict__ x,
                                             float* __restrict__ giout) {
    __shared__ __align__(16) float sst[8 * 4 * CHUNK];
    const int wave = threadIdx.x >> 6, lane = threadIdx.x & 63;
    float* st = sst + wave * 4 * CHUNK;
    const int row = blockIdx.x * 16 + wave * 2;               // 0..12286
    float r0, r1;
    mv2(gihW, row, H, H / CHUNK, x, st, lane, r0, r1);
    if (lane == 0) {
        giout[row]     = r0 + gihB[row];
        giout[row + 1] = r1 + gihB[row + 1];
    }
}

// K4: elementwise GRU gate math.
__global__ __launch_bounds__(256) void k_gate(const float* __restrict__ gi,
                                              const float* __restrict__ gh,
                                              const float* __restrict__ hidden,
                                              float* __restrict__ hout,
                                              float* __restrict__ out_h) {
    const int i = blockIdx.x * 256 + threadIdx.x;             // 0..4095
    float r = 1.f / (1.f + __expf(-(gi[i] + gh[i])));
    float z = 1.f / (1.f + __expf(-(gi[i + H] + gh[i + H])));
    float n = tanhf(gi[i + 2 * H] + r * gh[i + 2 * H]);
    float h = (1.f - z) * n + z * hidden[i];
    hout[i] = h;
    out_h[i] = h;
}

// K5: logits = out_W @ h_new + out_b. 256 blocks x 16 rows.
__global__ __launch_bounds__(512) void k_mvC(const float* __restrict__ outW,
                                             const float* __restrict__ outB,
                                             const float* __restrict__ h,
                                             float* __restrict__ logits) {
    __shared__ __align__(16) float sst[8 * 4 * CHUNK];
    const int wave = threadIdx.x >> 6, lane = threadIdx.x & 63;
    float* st = sst + wave * 4 * CHUNK;
    const int row = blockIdx.x * 16 + wave * 2;               // 0..4094
    float r0, r1;
    mv2(outW, row, H, H / CHUNK, h, st, lane, r0, r1);
    if (lane == 0) {
        logits[row]     = r0 + outB[row];
        logits[row + 1] = r1 + outB[row + 1];
    }
}

// K6: log_softmax over 4096 logits.
__global__ __launch_bounds__(1024) void k_lsm(const float* __restrict__ logits,
                                              float* __restrict__ out) {
    __shared__ float red[16];
    __shared__ float red2[16];
    const int tid = threadIdx.x, lane = tid & 63, wave = tid >> 6;
    float m = -1e30f;
    for (int k = tid; k < O; k += 1024) m = fmaxf(m, logits[k]);
    #pragma unroll
    for (int off = 32; off; off >>= 1) m = fmaxf(m, __shfl_down(m, off, 64));
    if (lane == 0) red[wave] = m;
    __syncthreads();
    if (tid == 0) {
        float mm = -1e30f;
        for (int j = 0; j < 16; j++) mm = fmaxf(mm, red[j]);
        red[0] = mm;
    }
    __syncthreads();
    m = red[0];
    float s = 0.f;
    for (int k = tid; k < O; k += 1024) s += __expf(logits[k] - m);
    #pragma unroll
    for (int off = 32; off; off >>= 1) s += __shfl_down(s, off, 64);
    if (lane == 0) red2[wave] = s;
    __syncthreads();
    if (tid == 0) {
        float ss = 0.f;
        for (int j = 0; j < 16; j++) ss += red2[j];
        red2[0] = m + logf(ss);
    }
    __syncthreads();
    float lse = red2[0];
    for (int k = tid; k < O; k += 1024) out[k] = logits[k] - lse;
}

extern "C" void kernel_launch(void* const* d_in, const int* in_sizes, int n_in,
                              void* d_out, int out_size, void* d_ws, size_t ws_size,
                              hipStream_t stream) {
    const int*   ids    = (const int*)d_in[0];
    const float* hidden = (const float*)d_in[1];
    // d_in[2] (e_output) unused by the reference
    const float* eseq   = (const float*)d_in[3];
    const float* embW   = (const float*)d_in[4];
    const float* attW   = (const float*)d_in[5];
    const float* attb   = (const float*)d_in[6];
    const float* combW  = (const float*)d_in[7];
    const float* combB  = (const float*)d_in[8];
    const float* gihW   = (const float*)d_in[9];
    const float* ghhW   = (const float*)d_in[10];
    const float* gihB   = (const float*)d_in[11];
    const float* ghhB   = (const float*)d_in[12];
    const float* outW   = (const float*)d_in[13];
    const float* outB   = (const float*)d_in[14];
    float* out = (float*)d_out;   // [log_softmax(4096) | h_new(4096) | att_w(15)]

    float* ws       = (float*)d_ws;
    float* combined = ws;              // 8192
    float* xbuf     = ws + 8192;       // 4096
    float* ghbuf    = ws + 12288;      // 12288
    float* gibuf    = ws + 24576;      // 12288
    float* hbuf     = ws + 36864;      // 4096
    float* logits   = ws + 40960;      // 4096
    float* attlog   = ws + 45056;      // 16

    k_attlogit<<<MAXLEN, 1024, 0, stream>>>(ids, hidden, embW, attW, attb, attlog);
    k_attapply<<<16,     256,  0, stream>>>(ids, embW, attlog, eseq, combined, out + 8192);
    k_mvA     <<<1024,   512,  0, stream>>>(combW, combB, ghhW, ghhB, hidden, combined, xbuf, ghbuf);
    k_mvB     <<<768,    512,  0, stream>>>(gihW, gihB, xbuf, gibuf);
    k_gate    <<<16,     256,  0, stream>>>(gibuf, ghbuf, hidden, hbuf, out + 4096);
    k_mvC     <<<256,    512,  0, stream>>>(outW, outB, hbuf, logits);
    k_lsm     <<<1,      1024, 0, stream>>>(logits, out);
}